// Round 14
// baseline (236.034 us; speedup 1.0000x reference)
//
#include <hip/hip_runtime.h>

#define LL 512
#define DIMV 128
#define AD 64
#define KK 32

#define S_I 530   // f32 words per i in S
#define S_J 33    // f32 words per j in S
#define U1I 2148  // u16 per i in U1
#define U1J 132   // u16 per j in U1

typedef __attribute__((ext_vector_type(8))) short bf16x8;
typedef __attribute__((ext_vector_type(4))) float f32x4;
typedef __attribute__((ext_vector_type(4))) unsigned short u16x4;
typedef __attribute__((ext_vector_type(8))) unsigned short u16x8;

#define MFMA(a,b,c) __builtin_amdgcn_mfma_f32_16x16x32_bf16(a,b,c,0,0,0)

__device__ __forceinline__ unsigned short f2bf(float f){
  unsigned u = __builtin_bit_cast(unsigned, f);
  u += 0x7FFFu + ((u >> 16) & 1u);          // RNE
  return (unsigned short)(u >> 16);
}
__device__ __forceinline__ float bf2f(unsigned short h){
  unsigned u = ((unsigned)h) << 16;
  return __builtin_bit_cast(float, u);
}

// ---------- fused: coverage partials (all 256 blocks) + weight prep (blocks 0-63) ----------
__global__ __launch_bounds__(256) void kprepcov(const float* __restrict__ td,
                      const float* __restrict__ Wg, const float* __restrict__ Wq,
                      float* __restrict__ part,
                      unsigned short* __restrict__ BTg, float* __restrict__ WqT){
  int t = threadIdx.x;
  if (blockIdx.x < 64){
    int idx = blockIdx.x*256 + t;
    {   // BTg: frag (ct,ks), lane (grp,rrow), elem e -> Wg[d=ks*32+grp*8+e][c=ct*16+rrow]
      int c = idx >> 7, d = idx & 127;
      int dest = ((c>>4)*4 + (d>>5))*512 + ((d>>3)&3)*128 + (c&15)*8 + (d&7);
      BTg[dest] = f2bf(Wg[d*128 + c]);
    }
    if (idx < 64*128){                        // WqT[a][d] = Wq[d][a]
      int a = idx >> 7, d = idx & 127;
      WqT[a*128 + d] = Wq[d*64 + a];
    }
  }
  __shared__ float red[256];
  float s = 0.f;
  for (int idx = blockIdx.x*256 + t; idx < LL*LL; idx += 256*256)
    s += (td[idx] > 0.f) ? 1.f : 0.f;
  red[t] = s; __syncthreads();
  for (int st = 128; st > 0; st >>= 1){ if (t < st) red[t] += red[t+st]; __syncthreads(); }
  if (t == 0) part[blockIdx.x] = red[0];
}

// ---------- gate MLP only ----------
__global__ __launch_bounds__(256) void kgate(const float* __restrict__ part, const float* __restrict__ tq,
                      const float* __restrict__ W1, const float* __restrict__ b1,
                      const float* __restrict__ W2, const float* __restrict__ b2,
                      float* __restrict__ gate_out){
  int t = threadIdx.x;
  __shared__ float red[256];
  red[t] = part[t]; __syncthreads();
  for (int st = 128; st > 0; st >>= 1){ if (t < st) red[t] += red[t+st]; __syncthreads(); }
  if (t == 0){
    float coverage = red[0] / (float)(LL*LL);
    float quality  = tq[0];
    float lennorm  = 1.0f;
    float sacc = 0.f;
    for (int j = 0; j < 16; j++){
      float hv = coverage*W1[0*16+j] + quality*W1[1*16+j] + lennorm*W1[2*16+j] + b1[j];
      hv = hv > 0.f ? hv : 0.f;
      sacc += hv * W2[j];
    }
    gate_out[0] = 1.f / (1.f + __expf(-(sacc + b2[0])));
  }
}

// ---------- projections: M1/M2 = Wq-folded left/right; voLT/voRTT = Wo-folded V ----------
__global__ __launch_bounds__(256) void kproj(const float* __restrict__ pr, const float* __restrict__ td,
                      const int* __restrict__ anchor,
                      const float* __restrict__ Wl, const float* __restrict__ Wr,
                      const float* __restrict__ Wvl, const float* __restrict__ Wvr,
                      const float* __restrict__ Wo, const float* __restrict__ WqT,
                      unsigned short* __restrict__ M1, unsigned short* __restrict__ M2,
                      unsigned short* __restrict__ voLT, unsigned short* __restrict__ voRTT,
                      float* __restrict__ tl, float* __restrict__ tr){
  int side = blockIdx.x >> 9;                // 0: col side (i), 1: row side (j)
  int r    = blockIdx.x & 511;
  int t = threadIdx.x, w = t >> 6, lane = t & 63;
  __shared__ float sX[32][128];
  __shared__ float sL[32][65];
  __shared__ float sV[32][65];
  const float* WL = side ? Wr  : Wl;
  const float* WV = side ? Wvr : Wvl;
  int kbase = w*8;
  for (int k8 = 0; k8 < 8; k8++){
    int ak = anchor[kbase + k8];
    const float* x = side ? (pr + ((size_t)ak*LL + r)*DIMV) : (pr + ((size_t)r*LL + ak)*DIMV);
    sX[kbase+k8][lane]    = x[lane];
    sX[kbase+k8][lane+64] = x[lane + 64];
  }
  if (lane < 8){
    int k = kbase + lane;
    int ak = anchor[k];
    float tv = side ? td[(size_t)ak*LL + r] : td[(size_t)r*LL + ak];
    (side ? tr : tl)[r*KK + k] = tv;
  }
  __syncthreads();
  float accL[8], accV[8];
  #pragma unroll
  for (int k8 = 0; k8 < 8; k8++){ accL[k8] = 0.f; accV[k8] = 0.f; }
  for (int d = 0; d < DIMV; d++){
    float wl = WL[d*AD + lane];
    float wv = WV[d*AD + lane];
    #pragma unroll
    for (int k8 = 0; k8 < 8; k8++){
      float xv = sX[kbase+k8][d];
      accL[k8] += xv*wl; accV[k8] += xv*wv;
    }
  }
  #pragma unroll
  for (int k8 = 0; k8 < 8; k8++){
    sL[kbase+k8][lane] = accL[k8];
    sV[kbase+k8][lane] = accV[k8];
  }
  __syncthreads();
  // phase2: M[k][d] = sum_a sL[k][a]*WqT[a][d];  voT[d][k] = sum_a sV[k][a]*Wo[a][d]
  int k = t & 31, dg = t >> 5;
  f32x4 accM[4], accO[4];
  f32x4 zf = {0.f,0.f,0.f,0.f};
  #pragma unroll
  for (int q = 0; q < 4; q++){ accM[q] = zf; accO[q] = zf; }
  for (int a = 0; a < AD; a++){
    float vl = sL[k][a];
    float vv = sV[k][a];
    const f32x4* wq = (const f32x4*)(WqT + a*128 + dg*16);
    const f32x4* wo = (const f32x4*)(Wo  + a*128 + dg*16);
    #pragma unroll
    for (int q = 0; q < 4; q++){
      accM[q] += wq[q]*vl;
      accO[q] += wo[q]*vv;
    }
  }
  unsigned short* M    = side ? M2    : M1;
  unsigned short* outV = side ? voRTT : voLT;
  #pragma unroll
  for (int q = 0; q < 4; q++){
    u16x4 pk;
    #pragma unroll
    for (int e = 0; e < 4; e++) pk[e] = f2bf(accM[q][e]);
    *(u16x4*)(M + ((size_t)r*KK + k)*DIMV + dg*16 + q*4) = pk;
  }
  #pragma unroll
  for (int q = 0; q < 4; q++)
    #pragma unroll
    for (int e = 0; e < 4; e++){
      int d = dg*16 + q*4 + e;
      outV[((size_t)r*DIMV + d)*KK + k] = f2bf(accO[q][e]);
    }
}

// ---------- mega kernel: scores + softmax + PV + g-GEMM fused epilogue (XCD-swizzled) ----------
__global__ __launch_bounds__(512, 4) void kmain(
    const float* __restrict__ pr, const float* __restrict__ td,
    const unsigned short* __restrict__ BTg, const float* __restrict__ bg,
    const unsigned short* __restrict__ M1, const unsigned short* __restrict__ M2,
    const unsigned short* __restrict__ voLT, const unsigned short* __restrict__ voRTT,
    const float* __restrict__ tl, const float* __restrict__ tr,
    const float* __restrict__ gatep,
    float* __restrict__ out){
  __shared__ __align__(16) char smem[68736];
  float* S = (float*)smem;                    // [16i][16j][32k]
  unsigned short* U1 = (unsigned short*)smem; // [16i][16j][128d] (aliased after S dies)
  // XCD-aware swizzle: wg&7 = XCD (round-robin dispatch); each XCD owns a 16bx x 8by region
  // so its L2 holds 16 M2/voRTT slices + 8 M1/voLT slices (~6.3 MB) instead of 8x replication.
  const int wg = blockIdx.x;
  const int xcd = wg & 7, l = wg >> 3;
  const int bx = (xcd & 1)*16 + (l & 15);
  const int by = (xcd >> 1)*8 + (l >> 4);
  const int i0 = by*16, j0 = bx*16;
  const int t = threadIdx.x, w = t >> 6, lane = t & 63;
  const int n = lane & 15, grp = lane >> 4;
  const float gate = gatep[0];
  const f32x4 zf = {0.f,0.f,0.f,0.f};

  // ---- phase A: pr A-frags (i = 2w+rt, j = n) — live through epilogue ----
  bf16x8 af[2][4];
  #pragma unroll
  for (int rt = 0; rt < 2; rt++){
    const float* p = pr + ((size_t)(i0 + 2*w + rt)*LL + j0 + n)*DIMV + grp*8;
    #pragma unroll
    for (int ks = 0; ks < 4; ks++){
      f32x4 lo = *(const f32x4*)(p + ks*32);
      f32x4 hi = *(const f32x4*)(p + ks*32 + 4);
      #pragma unroll
      for (int e = 0; e < 4; e++){ af[rt][ks][e] = (short)f2bf(lo[e]); af[rt][ks][4+e] = (short)f2bf(hi[e]); }
    }
  }
  // ---- early-issue term2 jj=0 raw A loads (cross barrier 1) ----
  f32x4 rawA[8];
  {
    const float* p = pr + ((size_t)(i0 + n)*LL + j0 + 2*w)*DIMV + grp*8;
    #pragma unroll
    for (int ks = 0; ks < 4; ks++){
      rawA[2*ks]   = *(const f32x4*)(p + ks*32);
      rawA[2*ks+1] = *(const f32x4*)(p + ks*32 + 4);
    }
  }
  // ---- term1: scores1[i][j][k] = pr[i,j] . M1[i,k]  (i = 2w+ii) ----
  #pragma unroll
  for (int ii = 0; ii < 2; ii++){
    int i = 2*w + ii;
    f32x4 acc[2]; acc[0] = zf; acc[1] = zf;
    #pragma unroll
    for (int kt = 0; kt < 2; kt++)
      #pragma unroll
      for (int ks = 0; ks < 4; ks++){
        bf16x8 b = *(const bf16x8*)(M1 + ((size_t)(i0+i)*KK + kt*16 + n)*DIMV + ks*32 + grp*8);
        acc[kt] = MFMA(af[ii][ks], b, acc[kt]);
      }
    #pragma unroll
    for (int kt = 0; kt < 2; kt++)
      #pragma unroll
      for (int rg = 0; rg < 4; rg++)
        S[i*S_I + (grp*4+rg)*S_J + kt*16 + n] = acc[kt][rg];
  }
  __syncthreads();
  // ---- term2 + bias (j = 2w+jj) ----
  #pragma unroll
  for (int jj = 0; jj < 2; jj++){
    int j = 2*w + jj;
    bf16x8 a2[4];
    if (jj == 0){
      #pragma unroll
      for (int ks = 0; ks < 4; ks++)
        #pragma unroll
        for (int e = 0; e < 4; e++){ a2[ks][e] = (short)f2bf(rawA[2*ks][e]); a2[ks][4+e] = (short)f2bf(rawA[2*ks+1][e]); }
    } else {
      const float* p = pr + ((size_t)(i0 + n)*LL + j0 + j)*DIMV + grp*8;
      #pragma unroll
      for (int ks = 0; ks < 4; ks++){
        f32x4 lo = *(const f32x4*)(p + ks*32);
        f32x4 hi = *(const f32x4*)(p + ks*32 + 4);
        #pragma unroll
        for (int e = 0; e < 4; e++){ a2[ks][e] = (short)f2bf(lo[e]); a2[ks][4+e] = (short)f2bf(hi[e]); }
      }
    }
    float tdv[4];
    #pragma unroll
    for (int rg = 0; rg < 4; rg++)
      tdv[rg] = td[(size_t)(i0 + grp*4 + rg)*LL + j0 + j];
    #pragma unroll
    for (int kt = 0; kt < 2; kt++){
      f32x4 acc = zf;
      #pragma unroll
      for (int ks = 0; ks < 4; ks++){
        bf16x8 b = *(const bf16x8*)(M2 + ((size_t)(j0+j)*KK + kt*16 + n)*DIMV + ks*32 + grp*8);
        acc = MFMA(a2[ks], b, acc);
      }
      #pragma unroll
      for (int rg = 0; rg < 4; rg++){
        int i = grp*4 + rg, k = kt*16 + n;
        float tb = tl[(i0+i)*KK + k] + tr[(j0+j)*KK + k] - tdv[rg];
        int idx = i*S_I + j*S_J + k;
        S[idx] = (S[idx] + acc[rg])*0.125f - gate*0.25f*fabsf(tb);
      }
    }
  }
  __syncthreads();
  // ---- softmax over k: 2 threads per (i,j) ----
  {
    int pair = t >> 1, half = t & 1;
    int i = pair >> 4, j = pair & 15;
    float* row = S + i*S_I + j*S_J + half*16;
    float v[16];
    float m = -1e30f;
    #pragma unroll
    for (int kk = 0; kk < 16; kk++){ v[kk] = row[kk]; m = fmaxf(m, v[kk]); }
    m = fmaxf(m, __shfl_xor(m, 1));
    float ss = 0.f;
    #pragma unroll
    for (int kk = 0; kk < 16; kk++){ v[kk] = __expf(v[kk] - m); ss += v[kk]; }
    ss += __shfl_xor(ss, 1);
    float rr = 1.0f / ss;
    #pragma unroll
    for (int kk = 0; kk < 16; kk++) row[kk] = v[kk]*rr;
  }
  __syncthreads();
  // ---- PV A-frags from S + early-issue PV1 ii=0 B-frags (cross alias barrier) ----
  bf16x8 pa1[2], pa2[2];
  #pragma unroll
  for (int ii = 0; ii < 2; ii++){
    #pragma unroll
    for (int e = 0; e < 8; e++) pa1[ii][e] = (short)f2bf(S[(2*w+ii)*S_I + n*S_J + grp*8 + e]);
    #pragma unroll
    for (int e = 0; e < 8; e++) pa2[ii][e] = (short)f2bf(S[n*S_I + (2*w+ii)*S_J + grp*8 + e]);
  }
  bf16x8 vb0[8];
  #pragma unroll
  for (int nt = 0; nt < 8; nt++)
    vb0[nt] = *(const bf16x8*)(voLT + ((size_t)(i0+2*w)*DIMV + nt*16 + n)*KK + grp*8);
  __syncthreads();                            // S dead -> U1 region live
  // ---- PV1: U1[i][j][d] = attn[i,j,:] @ voL[i,:,d] ----
  #pragma unroll
  for (int ii = 0; ii < 2; ii++){
    int i = 2*w + ii;
    #pragma unroll
    for (int nt = 0; nt < 8; nt++){
      bf16x8 b = ii ? *(const bf16x8*)(voLT + ((size_t)(i0+i)*DIMV + nt*16 + n)*KK + grp*8) : vb0[nt];
      f32x4 acc = MFMA(pa1[ii], b, zf);
      #pragma unroll
      for (int rg = 0; rg < 4; rg++)
        U1[i*U1I + (grp*4+rg)*U1J + nt*16 + n] = f2bf(acc[rg]);
    }
  }
  // early-issue PV2 jj=0 B-frags (cross barrier)
  bf16x8 vr0[8];
  #pragma unroll
  for (int nt = 0; nt < 8; nt++)
    vr0[nt] = *(const bf16x8*)(voRTT + ((size_t)(j0+2*w)*DIMV + nt*16 + n)*KK + grp*8);
  __syncthreads();
  // ---- PV2: accumulate ----
  #pragma unroll
  for (int jj = 0; jj < 2; jj++){
    int j = 2*w + jj;
    #pragma unroll
    for (int nt = 0; nt < 8; nt++){
      bf16x8 b = jj ? *(const bf16x8*)(voRTT + ((size_t)(j0+j)*DIMV + nt*16 + n)*KK + grp*8) : vr0[nt];
      f32x4 acc = MFMA(pa2[jj], b, zf);
      #pragma unroll
      for (int rg = 0; rg < 4; rg++){
        int idx = (grp*4+rg)*U1I + j*U1J + nt*16 + n;
        U1[idx] = f2bf(bf2f(U1[idx]) + acc[rg]);
      }
    }
  }
  // early-issue epilogue ct=0 BTg frags (cross barrier)
  bf16x8 bt0[4];
  #pragma unroll
  for (int ks = 0; ks < 4; ks++)
    bt0[ks] = *(const bf16x8*)(BTg + ks*512 + lane*8);
  __syncthreads();
  // ---- epilogue: g-GEMM per ct (zero live range) + residual + store ----
  #pragma unroll
  for (int rt = 0; rt < 2; rt++){
    int i = 2*w + rt;
    #pragma unroll
    for (int ct = 0; ct < 8; ct++){
      f32x4 acc = zf;
      #pragma unroll
      for (int ks = 0; ks < 4; ks++){
        bf16x8 b = ct ? *(const bf16x8*)(BTg + (ct*4 + ks)*512 + lane*8) : bt0[ks];
        acc = MFMA(af[rt][ks], b, acc);
      }
      float bgv = bg[ct*16 + n];
      #pragma unroll
      for (int rg = 0; rg < 4; rg++){
        int jl = grp*4 + rg, d = ct*16 + n;
        float gg = 1.f/(1.f + __expf(-(acc[rg] + bgv)));
        float u = bf2f(U1[i*U1I + jl*U1J + d]);
        size_t gi = ((size_t)(i0+i)*LL + j0 + jl)*DIMV + d;
        out[gi] = pr[gi] + gg*u;
      }
    }
  }
}

extern "C" void kernel_launch(void* const* d_in, const int* in_sizes, int n_in,
                              void* d_out, int out_size, void* d_ws, size_t ws_size,
                              hipStream_t stream){
  const float* pr  = (const float*)d_in[0];
  const float* td  = (const float*)d_in[1];
  const float* tq  = (const float*)d_in[2];
  const float* Wq  = (const float*)d_in[3];
  const float* Wl  = (const float*)d_in[4];
  const float* Wr  = (const float*)d_in[5];
  const float* Wvl = (const float*)d_in[6];
  const float* Wvr = (const float*)d_in[7];
  const float* Wo  = (const float*)d_in[8];
  const float* Wg  = (const float*)d_in[9];
  const float* bg  = (const float*)d_in[10];
  const float* W1  = (const float*)d_in[11];
  const float* b1  = (const float*)d_in[12];
  const float* W2  = (const float*)d_in[13];
  const float* b2  = (const float*)d_in[14];
  const int* anchor = (const int*)d_in[15];
  float* out = (float*)d_out;

  char* ws = (char*)d_ws;
  size_t off = 0;
  auto alloc = [&](size_t bytes)->void*{ void* p = ws + off; off += (bytes + 255) & ~(size_t)255; return p; };
  float* g_gate  = (float*)alloc(4);
  float* g_part  = (float*)alloc(256*4);
  float* g_tl    = (float*)alloc((size_t)LL*KK*4);
  float* g_tr    = (float*)alloc((size_t)LL*KK*4);
  unsigned short* g_BTg  = (unsigned short*)alloc((size_t)128*128*2);
  float*          g_WqT  = (float*)alloc((size_t)64*128*4);
  unsigned short* g_M1   = (unsigned short*)alloc((size_t)LL*KK*DIMV*2);
  unsigned short* g_M2   = (unsigned short*)alloc((size_t)LL*KK*DIMV*2);
  unsigned short* g_voLT = (unsigned short*)alloc((size_t)LL*DIMV*KK*2);
  unsigned short* g_voRTT= (unsigned short*)alloc((size_t)LL*DIMV*KK*2);
  (void)ws_size; (void)in_sizes; (void)n_in; (void)out_size;

  kprepcov<<<256, 256, 0, stream>>>(td, Wg, Wq, g_part, g_BTg, g_WqT);
  kgate<<<1,   256, 0, stream>>>(g_part, tq, W1, b1, W2, b2, g_gate);
  kproj<<<1024,256, 0, stream>>>(pr, td, anchor, Wl, Wr, Wvl, Wvr, Wo, g_WqT,
                                 g_M1, g_M2, g_voLT, g_voRTT, g_tl, g_tr);
  kmain<<<1024, 512, 0, stream>>>(pr, td, g_BTg, bg, g_M1, g_M2,
                                  g_voLT, g_voRTT, g_tl, g_tr, g_gate, out);
}

// Round 15
// 160.254 us; speedup vs baseline: 1.4729x; 1.4729x over previous
//
#include <hip/hip_runtime.h>

#define LL 512
#define DIMV 128
#define AD 64
#define KK 32

#define S_I 530   // f32 words per i in S
#define S_J 33    // f32 words per j in S
#define U1I 2148  // u16 per i in U1
#define U1J 132   // u16 per j in U1
#define XST 136   // u16 stride sX row
#define LVST 68   // u16 stride sLV row

typedef __attribute__((ext_vector_type(8))) short bf16x8;
typedef __attribute__((ext_vector_type(4))) float f32x4;
typedef __attribute__((ext_vector_type(4))) unsigned short u16x4;
typedef __attribute__((ext_vector_type(8))) unsigned short u16x8;

#define MFMA(a,b,c) __builtin_amdgcn_mfma_f32_16x16x32_bf16(a,b,c,0,0,0)

__device__ __forceinline__ unsigned short f2bf(float f){
  unsigned u = __builtin_bit_cast(unsigned, f);
  u += 0x7FFFu + ((u >> 16) & 1u);          // RNE
  return (unsigned short)(u >> 16);
}
__device__ __forceinline__ float bf2f(unsigned short h){
  unsigned u = ((unsigned)h) << 16;
  return __builtin_bit_cast(float, u);
}

// frag-ordered dest for a [cols x inner] B-matrix, 16x16x32 frags:
// elem = src(inner = ks*32+grp*8+e, col = ct*16+rrow); dest block (ct*KS+ks)*512 + grp*128 + rrow*8 + e
__device__ __forceinline__ int fragdest(int c, int k, int KS){
  return ((c>>4)*KS + (k>>5))*512 + ((k>>3)&3)*128 + (c&15)*8 + (k&7);
}

// ---------- fused: coverage partials (256 blocks) + ALL weight prep ----------
__global__ __launch_bounds__(256) void kprepcov(const float* __restrict__ td,
                      const float* __restrict__ Wg, const float* __restrict__ Wq,
                      const float* __restrict__ Wl, const float* __restrict__ Wr,
                      const float* __restrict__ Wvl, const float* __restrict__ Wvr,
                      const float* __restrict__ Wo,
                      float* __restrict__ part,
                      unsigned short* __restrict__ BTg,
                      unsigned short* __restrict__ FWl, unsigned short* __restrict__ FWr,
                      unsigned short* __restrict__ FWvl, unsigned short* __restrict__ FWvr,
                      unsigned short* __restrict__ FQ, unsigned short* __restrict__ FO){
  int t = threadIdx.x;
  int b = blockIdx.x;
  if (b < 64){                                // BTg: cols=128 (Wg out), inner=128
    int idx = b*256 + t;
    int c = idx >> 7, d = idx & 127;
    BTg[fragdest(c, d, 4)] = f2bf(Wg[d*128 + c]);
  } else if (b < 96){                         // FWl/FWr: cols=64 (a), inner=128 (d)
    int idx = (b-64)*256 + t;                 // idx = c*128 + d
    int c = idx >> 7, d = idx & 127;
    int dst = fragdest(c, d, 4);
    FWl[dst] = f2bf(Wl[d*64 + c]);
    FWr[dst] = f2bf(Wr[d*64 + c]);
  } else if (b < 128){                        // FWvl/FWvr
    int idx = (b-96)*256 + t;
    int c = idx >> 7, d = idx & 127;
    int dst = fragdest(c, d, 4);
    FWvl[dst] = f2bf(Wvl[d*64 + c]);
    FWvr[dst] = f2bf(Wvr[d*64 + c]);
  } else if (b < 160){                        // FQ/FO: cols=128 (d), inner=64 (a)
    int idx = (b-128)*256 + t;                // idx = c*64 + a
    int c = idx >> 6, a = idx & 63;
    int dst = fragdest(c, a, 2);
    FQ[dst] = f2bf(Wq[c*64 + a]);             // Wq[d][a]
    FO[dst] = f2bf(Wo[a*128 + c]);            // Wo[a][d]
  }
  __shared__ float red[256];
  float s = 0.f;
  for (int idx = b*256 + t; idx < LL*LL; idx += 256*256)
    s += (td[idx] > 0.f) ? 1.f : 0.f;
  red[t] = s; __syncthreads();
  for (int st = 128; st > 0; st >>= 1){ if (t < st) red[t] += red[t+st]; __syncthreads(); }
  if (t == 0) part[b] = red[0];
}

// ---------- projections (MFMA) + fused gate MLP in block 0 ----------
__global__ __launch_bounds__(256) void kproj(const float* __restrict__ pr, const float* __restrict__ td,
                      const int* __restrict__ anchor,
                      const unsigned short* __restrict__ FWl, const unsigned short* __restrict__ FWr,
                      const unsigned short* __restrict__ FWvl, const unsigned short* __restrict__ FWvr,
                      const unsigned short* __restrict__ FQ, const unsigned short* __restrict__ FO,
                      const float* __restrict__ part, const float* __restrict__ tq,
                      const float* __restrict__ W1, const float* __restrict__ b1,
                      const float* __restrict__ W2, const float* __restrict__ b2,
                      unsigned short* __restrict__ M1, unsigned short* __restrict__ M2,
                      unsigned short* __restrict__ voLT, unsigned short* __restrict__ voRTT,
                      float* __restrict__ tl, float* __restrict__ tr,
                      float* __restrict__ gate_out){
  int side = blockIdx.x >> 9;                // 0: col side (i), 1: row side (j)
  int r    = blockIdx.x & 511;
  int t = threadIdx.x, w = t >> 6, lane = t & 63;
  int n = lane & 15, grp = lane >> 4;
  __shared__ unsigned short sX[32*XST];      // [32 k][128 d] bf16
  __shared__ unsigned short sLV[2*32*LVST];  // [mat][32 k][64 a] bf16
  __shared__ float red[256];
  const f32x4 zf = {0.f,0.f,0.f,0.f};

  // fused gate MLP (block 0 only; part[] written by previous launch)
  if (blockIdx.x == 0){
    red[t] = part[t]; __syncthreads();
    for (int st = 128; st > 0; st >>= 1){ if (t < st) red[t] += red[t+st]; __syncthreads(); }
    if (t == 0){
      float coverage = red[0] / (float)(LL*LL);
      float quality  = tq[0];
      float sacc = 0.f;
      for (int j = 0; j < 16; j++){
        float hv = coverage*W1[0*16+j] + quality*W1[1*16+j] + 1.0f*W1[2*16+j] + b1[j];
        hv = hv > 0.f ? hv : 0.f;
        sacc += hv * W2[j];
      }
      gate_out[0] = 1.f / (1.f + __expf(-(sacc + b2[0])));
    }
    __syncthreads();
  }

  // ---- gather X rows (bf16) + t-tables ----
  int kbase = w*8;
  for (int k8 = 0; k8 < 8; k8++){
    int ak = anchor[kbase + k8];
    const float* x = side ? (pr + ((size_t)ak*LL + r)*DIMV) : (pr + ((size_t)r*LL + ak)*DIMV);
    sX[(kbase+k8)*XST + lane]      = f2bf(x[lane]);
    sX[(kbase+k8)*XST + lane + 64] = f2bf(x[lane + 64]);
  }
  if (lane < 8){
    int k = kbase + lane;
    int ak = anchor[k];
    float tv = side ? td[(size_t)ak*LL + r] : td[(size_t)r*LL + ak];
    (side ? tr : tl)[r*KK + k] = tv;
  }
  __syncthreads();
  // ---- phase1 (MFMA): C[k][a] = X @ W  — wave w: kt = w&1, mat = w>>1 (0=L,1=V) ----
  {
    int kt = w & 1, mat = w >> 1;
    const unsigned short* FW = mat ? (side ? FWvr : FWvl) : (side ? FWr : FWl);
    bf16x8 afr[4];
    #pragma unroll
    for (int ks = 0; ks < 4; ks++)
      afr[ks] = *(const bf16x8*)(&sX[(kt*16 + n)*XST + ks*32 + grp*8]);
    #pragma unroll
    for (int ct = 0; ct < 4; ct++){
      f32x4 acc = zf;
      #pragma unroll
      for (int ks = 0; ks < 4; ks++)
        acc = MFMA(afr[ks], *(const bf16x8*)(FW + (ct*4 + ks)*512 + lane*8), acc);
      #pragma unroll
      for (int rg = 0; rg < 4; rg++)
        sLV[mat*32*LVST + (kt*16 + grp*4 + rg)*LVST + ct*16 + n] = f2bf(acc[rg]);
    }
  }
  __syncthreads();
  // ---- phase2 (MFMA): M[k][d] = L @ FQ ; voT = (V @ FO)^T — wave w: kt = w&1, mat = w>>1 ----
  {
    int kt = w & 1, mat = w >> 1;
    const unsigned short* FB = mat ? FO : FQ;
    bf16x8 afr[2];
    #pragma unroll
    for (int ks = 0; ks < 2; ks++)
      afr[ks] = *(const bf16x8*)(&sLV[mat*32*LVST + (kt*16 + n)*LVST + ks*32 + grp*8]);
    unsigned short* Mout = side ? M2 : M1;
    unsigned short* Vout = side ? voRTT : voLT;
    #pragma unroll
    for (int ct = 0; ct < 8; ct++){
      f32x4 acc = zf;
      #pragma unroll
      for (int ks = 0; ks < 2; ks++)
        acc = MFMA(afr[ks], *(const bf16x8*)(FB + (ct*2 + ks)*512 + lane*8), acc);
      #pragma unroll
      for (int rg = 0; rg < 4; rg++){
        int k = kt*16 + grp*4 + rg, d = ct*16 + n;
        if (mat == 0) Mout[((size_t)r*KK + k)*DIMV + d] = f2bf(acc[rg]);
        else          Vout[((size_t)r*DIMV + d)*KK + k] = f2bf(acc[rg]);
      }
    }
  }
}

// ---------- mega kernel (R13-exact): scores + softmax + PV + g-GEMM fused epilogue ----------
__global__ __launch_bounds__(512, 4) void kmain(
    const float* __restrict__ pr, const float* __restrict__ td,
    const unsigned short* __restrict__ BTg, const float* __restrict__ bg,
    const unsigned short* __restrict__ M1, const unsigned short* __restrict__ M2,
    const unsigned short* __restrict__ voLT, const unsigned short* __restrict__ voRTT,
    const float* __restrict__ tl, const float* __restrict__ tr,
    const float* __restrict__ gatep,
    float* __restrict__ out){
  __shared__ __align__(16) char smem[68736];
  float* S = (float*)smem;                    // [16i][16j][32k]
  unsigned short* U1 = (unsigned short*)smem; // [16i][16j][128d] (aliased after S dies)
  const int i0 = blockIdx.y*16, j0 = blockIdx.x*16;
  const int t = threadIdx.x, w = t >> 6, lane = t & 63;
  const int n = lane & 15, grp = lane >> 4;
  const float gate = gatep[0];
  const f32x4 zf = {0.f,0.f,0.f,0.f};

  // ---- phase A: pr A-frags (i = 2w+rt, j = n) — live through epilogue ----
  bf16x8 af[2][4];
  #pragma unroll
  for (int rt = 0; rt < 2; rt++){
    const float* p = pr + ((size_t)(i0 + 2*w + rt)*LL + j0 + n)*DIMV + grp*8;
    #pragma unroll
    for (int ks = 0; ks < 4; ks++){
      f32x4 lo = *(const f32x4*)(p + ks*32);
      f32x4 hi = *(const f32x4*)(p + ks*32 + 4);
      #pragma unroll
      for (int e = 0; e < 4; e++){ af[rt][ks][e] = (short)f2bf(lo[e]); af[rt][ks][4+e] = (short)f2bf(hi[e]); }
    }
  }
  // ---- early-issue term2 jj=0 raw A loads (cross barrier 1) ----
  f32x4 rawA[8];
  {
    const float* p = pr + ((size_t)(i0 + n)*LL + j0 + 2*w)*DIMV + grp*8;
    #pragma unroll
    for (int ks = 0; ks < 4; ks++){
      rawA[2*ks]   = *(const f32x4*)(p + ks*32);
      rawA[2*ks+1] = *(const f32x4*)(p + ks*32 + 4);
    }
  }
  // ---- term1: scores1[i][j][k] = pr[i,j] . M1[i,k]  (i = 2w+ii) ----
  #pragma unroll
  for (int ii = 0; ii < 2; ii++){
    int i = 2*w + ii;
    f32x4 acc[2]; acc[0] = zf; acc[1] = zf;
    #pragma unroll
    for (int kt = 0; kt < 2; kt++)
      #pragma unroll
      for (int ks = 0; ks < 4; ks++){
        bf16x8 b = *(const bf16x8*)(M1 + ((size_t)(i0+i)*KK + kt*16 + n)*DIMV + ks*32 + grp*8);
        acc[kt] = MFMA(af[ii][ks], b, acc[kt]);
      }
    #pragma unroll
    for (int kt = 0; kt < 2; kt++)
      #pragma unroll
      for (int rg = 0; rg < 4; rg++)
        S[i*S_I + (grp*4+rg)*S_J + kt*16 + n] = acc[kt][rg];
  }
  __syncthreads();
  // ---- term2 + bias (j = 2w+jj) ----
  #pragma unroll
  for (int jj = 0; jj < 2; jj++){
    int j = 2*w + jj;
    bf16x8 a2[4];
    if (jj == 0){
      #pragma unroll
      for (int ks = 0; ks < 4; ks++)
        #pragma unroll
        for (int e = 0; e < 4; e++){ a2[ks][e] = (short)f2bf(rawA[2*ks][e]); a2[ks][4+e] = (short)f2bf(rawA[2*ks+1][e]); }
    } else {
      const float* p = pr + ((size_t)(i0 + n)*LL + j0 + j)*DIMV + grp*8;
      #pragma unroll
      for (int ks = 0; ks < 4; ks++){
        f32x4 lo = *(const f32x4*)(p + ks*32);
        f32x4 hi = *(const f32x4*)(p + ks*32 + 4);
        #pragma unroll
        for (int e = 0; e < 4; e++){ a2[ks][e] = (short)f2bf(lo[e]); a2[ks][4+e] = (short)f2bf(hi[e]); }
      }
    }
    float tdv[4];
    #pragma unroll
    for (int rg = 0; rg < 4; rg++)
      tdv[rg] = td[(size_t)(i0 + grp*4 + rg)*LL + j0 + j];
    #pragma unroll
    for (int kt = 0; kt < 2; kt++){
      f32x4 acc = zf;
      #pragma unroll
      for (int ks = 0; ks < 4; ks++){
        bf16x8 b = *(const bf16x8*)(M2 + ((size_t)(j0+j)*KK + kt*16 + n)*DIMV + ks*32 + grp*8);
        acc = MFMA(a2[ks], b, acc);
      }
      #pragma unroll
      for (int rg = 0; rg < 4; rg++){
        int i = grp*4 + rg, k = kt*16 + n;
        float tb = tl[(i0+i)*KK + k] + tr[(j0+j)*KK + k] - tdv[rg];
        int idx = i*S_I + j*S_J + k;
        S[idx] = (S[idx] + acc[rg])*0.125f - gate*0.25f*fabsf(tb);
      }
    }
  }
  __syncthreads();
  // ---- softmax over k: 2 threads per (i,j) ----
  {
    int pair = t >> 1, half = t & 1;
    int i = pair >> 4, j = pair & 15;
    float* row = S + i*S_I + j*S_J + half*16;
    float v[16];
    float m = -1e30f;
    #pragma unroll
    for (int kk = 0; kk < 16; kk++){ v[kk] = row[kk]; m = fmaxf(m, v[kk]); }
    m = fmaxf(m, __shfl_xor(m, 1));
    float ss = 0.f;
    #pragma unroll
    for (int kk = 0; kk < 16; kk++){ v[kk] = __expf(v[kk] - m); ss += v[kk]; }
    ss += __shfl_xor(ss, 1);
    float rr = 1.0f / ss;
    #pragma unroll
    for (int kk = 0; kk < 16; kk++) row[kk] = v[kk]*rr;
  }
  __syncthreads();
  // ---- PV A-frags from S + early-issue PV1 ii=0 B-frags (cross alias barrier) ----
  bf16x8 pa1[2], pa2[2];
  #pragma unroll
  for (int ii = 0; ii < 2; ii++){
    #pragma unroll
    for (int e = 0; e < 8; e++) pa1[ii][e] = (short)f2bf(S[(2*w+ii)*S_I + n*S_J + grp*8 + e]);
    #pragma unroll
    for (int e = 0; e < 8; e++) pa2[ii][e] = (short)f2bf(S[n*S_I + (2*w+ii)*S_J + grp*8 + e]);
  }
  bf16x8 vb0[8];
  #pragma unroll
  for (int nt = 0; nt < 8; nt++)
    vb0[nt] = *(const bf16x8*)(voLT + ((size_t)(i0+2*w)*DIMV + nt*16 + n)*KK + grp*8);
  __syncthreads();                            // S dead -> U1 region live
  // ---- PV1: U1[i][j][d] = attn[i,j,:] @ voL[i,:,d] ----
  #pragma unroll
  for (int ii = 0; ii < 2; ii++){
    int i = 2*w + ii;
    #pragma unroll
    for (int nt = 0; nt < 8; nt++){
      bf16x8 b = ii ? *(const bf16x8*)(voLT + ((size_t)(i0+i)*DIMV + nt*16 + n)*KK + grp*8) : vb0[nt];
      f32x4 acc = MFMA(pa1[ii], b, zf);
      #pragma unroll
      for (int rg = 0; rg < 4; rg++)
        U1[i*U1I + (grp*4+rg)*U1J + nt*16 + n] = f2bf(acc[rg]);
    }
  }
  // early-issue PV2 jj=0 B-frags (cross barrier)
  bf16x8 vr0[8];
  #pragma unroll
  for (int nt = 0; nt < 8; nt++)
    vr0[nt] = *(const bf16x8*)(voRTT + ((size_t)(j0+2*w)*DIMV + nt*16 + n)*KK + grp*8);
  __syncthreads();
  // ---- PV2: accumulate ----
  #pragma unroll
  for (int jj = 0; jj < 2; jj++){
    int j = 2*w + jj;
    #pragma unroll
    for (int nt = 0; nt < 8; nt++){
      bf16x8 b = jj ? *(const bf16x8*)(voRTT + ((size_t)(j0+j)*DIMV + nt*16 + n)*KK + grp*8) : vr0[nt];
      f32x4 acc = MFMA(pa2[jj], b, zf);
      #pragma unroll
      for (int rg = 0; rg < 4; rg++){
        int idx = (grp*4+rg)*U1I + j*U1J + nt*16 + n;
        U1[idx] = f2bf(bf2f(U1[idx]) + acc[rg]);
      }
    }
  }
  // early-issue epilogue ct=0 BTg frags (cross barrier)
  bf16x8 bt0[4];
  #pragma unroll
  for (int ks = 0; ks < 4; ks++)
    bt0[ks] = *(const bf16x8*)(BTg + ks*512 + lane*8);
  __syncthreads();
  // ---- epilogue: g-GEMM per ct (zero live range) + residual + store ----
  #pragma unroll
  for (int rt = 0; rt < 2; rt++){
    int i = 2*w + rt;
    #pragma unroll
    for (int ct = 0; ct < 8; ct++){
      f32x4 acc = zf;
      #pragma unroll
      for (int ks = 0; ks < 4; ks++){
        bf16x8 b = ct ? *(const bf16x8*)(BTg + (ct*4 + ks)*512 + lane*8) : bt0[ks];
        acc = MFMA(af[rt][ks], b, acc);
      }
      float bgv = bg[ct*16 + n];
      #pragma unroll
      for (int rg = 0; rg < 4; rg++){
        int jl = grp*4 + rg, d = ct*16 + n;
        float gg = 1.f/(1.f + __expf(-(acc[rg] + bgv)));
        float u = bf2f(U1[i*U1I + jl*U1J + d]);
        size_t gi = ((size_t)(i0+i)*LL + j0 + jl)*DIMV + d;
        out[gi] = pr[gi] + gg*u;
      }
    }
  }
}

extern "C" void kernel_launch(void* const* d_in, const int* in_sizes, int n_in,
                              void* d_out, int out_size, void* d_ws, size_t ws_size,
                              hipStream_t stream){
  const float* pr  = (const float*)d_in[0];
  const float* td  = (const float*)d_in[1];
  const float* tq  = (const float*)d_in[2];
  const float* Wq  = (const float*)d_in[3];
  const float* Wl  = (const float*)d_in[4];
  const float* Wr  = (const float*)d_in[5];
  const float* Wvl = (const float*)d_in[6];
  const float* Wvr = (const float*)d_in[7];
  const float* Wo  = (const float*)d_in[8];
  const float* Wg  = (const float*)d_in[9];
  const float* bg  = (const float*)d_in[10];
  const float* W1  = (const float*)d_in[11];
  const float* b1  = (const float*)d_in[12];
  const float* W2  = (const float*)d_in[13];
  const float* b2  = (const float*)d_in[14];
  const int* anchor = (const int*)d_in[15];
  float* out = (float*)d_out;

  char* ws = (char*)d_ws;
  size_t off = 0;
  auto alloc = [&](size_t bytes)->void*{ void* p = ws + off; off += (bytes + 255) & ~(size_t)255; return p; };
  float* g_gate  = (float*)alloc(4);
  float* g_part  = (float*)alloc(256*4);
  float* g_tl    = (float*)alloc((size_t)LL*KK*4);
  float* g_tr    = (float*)alloc((size_t)LL*KK*4);
  unsigned short* g_BTg  = (unsigned short*)alloc((size_t)128*128*2);
  unsigned short* g_FWl  = (unsigned short*)alloc((size_t)64*128*2);
  unsigned short* g_FWr  = (unsigned short*)alloc((size_t)64*128*2);
  unsigned short* g_FWvl = (unsigned short*)alloc((size_t)64*128*2);
  unsigned short* g_FWvr = (unsigned short*)alloc((size_t)64*128*2);
  unsigned short* g_FQ   = (unsigned short*)alloc((size_t)128*64*2);
  unsigned short* g_FO   = (unsigned short*)alloc((size_t)128*64*2);
  unsigned short* g_M1   = (unsigned short*)alloc((size_t)LL*KK*DIMV*2);
  unsigned short* g_M2   = (unsigned short*)alloc((size_t)LL*KK*DIMV*2);
  unsigned short* g_voLT = (unsigned short*)alloc((size_t)LL*DIMV*KK*2);
  unsigned short* g_voRTT= (unsigned short*)alloc((size_t)LL*DIMV*KK*2);
  (void)ws_size; (void)in_sizes; (void)n_in; (void)out_size;

  kprepcov<<<256, 256, 0, stream>>>(td, Wg, Wq, Wl, Wr, Wvl, Wvr, Wo, g_part,
                                    g_BTg, g_FWl, g_FWr, g_FWvl, g_FWvr, g_FQ, g_FO);
  kproj<<<1024, 256, 0, stream>>>(pr, td, anchor, g_FWl, g_FWr, g_FWvl, g_FWvr,
                                  g_FQ, g_FO, g_part, tq, W1, b1, W2, b2,
                                  g_M1, g_M2, g_voLT, g_voRTT, g_tl, g_tr, g_gate);
  kmain<<<dim3(32,32), 512, 0, stream>>>(pr, td, g_BTg, bg, g_M1, g_M2,
                                         g_voLT, g_voRTT, g_tl, g_tr, g_gate, out);
}